// Round 6
// baseline (779.353 us; speedup 1.0000x reference)
//
#include <hip/hip_runtime.h>
#include <math.h>

// Problem constants
#define BDIM 4096
#define NEXP 8
#define HDIM 1024
#define XDIM 800
#define ZDIM 64
#define ODIM 768
#define GH   128

typedef _Float16 f16;
typedef f16   f16x8 __attribute__((ext_vector_type(8)));
typedef f16   f16x4 __attribute__((ext_vector_type(4)));
typedef float f32x4 __attribute__((ext_vector_type(4)));

__device__ __forceinline__ float elu_act(float x) {
    return x > 0.0f ? x : expm1f(x);
}

__device__ __forceinline__ f16x8 vscale(f16x8 v, f16 s) {
    f16x8 r;
    #pragma unroll
    for (int i = 0; i < 8; ++i) r[i] = v[i] * s;
    return r;
}

// ===========================================================================
// Fused gating MLP (fp32) + softmax + hz z-column fill.
// One block = 16 rows. Phases:
//  0: stage xz rows to LDS; write f16(z) into z-cols of hz_a/hz_b
//  1: g1 = elu(xz @ Wg1^T + bg1)      (864 -> 128)
//  2: g2 = elu(g1 @ Wg2^T + bg2)      (128 -> 128)
//  3: bc = softmax(g2 @ Wg3^T + bg3)  (128 -> 8), shfl-softmax over 8 lanes
// ===========================================================================
__global__ __launch_bounds__(256)
void gating_fused(const float* __restrict__ x, const float* __restrict__ z,
                  const float* __restrict__ Wg1, const float* __restrict__ bg1,
                  const float* __restrict__ Wg2, const float* __restrict__ bg2,
                  const float* __restrict__ Wg3, const float* __restrict__ bg3,
                  float* __restrict__ bc, f16* __restrict__ hz_a,
                  f16* __restrict__ hz_b)
{
    __shared__ float xz_sh[16][868];   // 864 + 4 pad
    __shared__ float g1_sh[16][136];
    __shared__ float g2_sh[16][136];

    const int tid = threadIdx.x;
    const int r0  = blockIdx.x * 16;

    // phase 0: stage x (16x800) and z (16x64) as float4
    for (int i = tid; i < 16 * 200; i += 256) {
        int r = i / 200, c4 = i - r * 200;
        float4 v = *(const float4*)(x + (size_t)(r0 + r) * XDIM + c4 * 4);
        *(float4*)&xz_sh[r][c4 * 4] = v;
    }
    {
        int i = tid;
        if (i < 256) {
            int r = i >> 4, c4 = i & 15;
            float4 v = *(const float4*)(z + (size_t)(r0 + r) * ZDIM + c4 * 4);
            *(float4*)&xz_sh[r][XDIM + c4 * 4] = v;
            f16x4 h = { (f16)v.x, (f16)v.y, (f16)v.z, (f16)v.w };
            size_t off = (size_t)(r0 + r) * (HDIM + ZDIM) + HDIM + c4 * 4;
            *(f16x4*)(hz_a + off) = h;
            *(f16x4*)(hz_b + off) = h;
        }
    }
    __syncthreads();

    const int rr = tid >> 4;     // 0..15
    const int ob = tid & 15;     // o = ob + 16*j

    // phase 1: g1 (K=864)
    {
        float accg[8];
        #pragma unroll
        for (int j = 0; j < 8; ++j) accg[j] = bg1[ob + 16 * j];
        for (int k4 = 0; k4 < 216; ++k4) {
            float4 xv = *(const float4*)&xz_sh[rr][k4 * 4];
            #pragma unroll
            for (int j = 0; j < 8; ++j) {
                float4 wv = *(const float4*)(Wg1 + (size_t)(ob + 16 * j) * 864 + k4 * 4);
                accg[j] += xv.x * wv.x + xv.y * wv.y + xv.z * wv.z + xv.w * wv.w;
            }
        }
        #pragma unroll
        for (int j = 0; j < 8; ++j) g1_sh[rr][ob + 16 * j] = elu_act(accg[j]);
    }
    __syncthreads();

    // phase 2: g2 (K=128)
    {
        float accg[8];
        #pragma unroll
        for (int j = 0; j < 8; ++j) accg[j] = bg2[ob + 16 * j];
        for (int k4 = 0; k4 < 32; ++k4) {
            float4 xv = *(const float4*)&g1_sh[rr][k4 * 4];
            #pragma unroll
            for (int j = 0; j < 8; ++j) {
                float4 wv = *(const float4*)(Wg2 + (size_t)(ob + 16 * j) * GH + k4 * 4);
                accg[j] += xv.x * wv.x + xv.y * wv.y + xv.z * wv.z + xv.w * wv.w;
            }
        }
        #pragma unroll
        for (int j = 0; j < 8; ++j) g2_sh[rr][ob + 16 * j] = elu_act(accg[j]);
    }
    __syncthreads();

    // phase 3: logits + softmax (threads 0..127: row=tid>>3, e=tid&7)
    if (tid < 128) {
        int r = tid >> 3, e = tid & 7;
        float s = bg3[e];
        for (int k4 = 0; k4 < 32; ++k4) {
            float4 xv = *(const float4*)&g2_sh[r][k4 * 4];
            float4 wv = *(const float4*)(Wg3 + (size_t)e * GH + k4 * 4);
            s += xv.x * wv.x + xv.y * wv.y + xv.z * wv.z + xv.w * wv.w;
        }
        float m = s;
        #pragma unroll
        for (int d = 4; d >= 1; d >>= 1) m = fmaxf(m, __shfl_xor(m, d, 8));
        float ex = expf(s - m);
        float sum = ex;
        #pragma unroll
        for (int d = 4; d >= 1; d >>= 1) sum += __shfl_xor(sum, d, 8);
        bc[(size_t)(r0 + r) * NEXP + e] = ex / sum;
    }
}

// ===========================================================================
// Weight conversion fp32 -> f16 in MFMA B-frag tiled layout:
//   Wt[(e*(N/16) + nt)*(K/32) + kc][lane][8] where
//   element (lane, j) = W[e][nt*16 + (lane&15)][kc*32 + (lane>>4)*8 + j]
// ===========================================================================
template<int N, int K>
__global__ __launch_bounds__(256)
void w_tile(const float* __restrict__ W, f16* __restrict__ Wt)
{
    constexpr int KC = K / 32;
    size_t i = (size_t)blockIdx.x * 256 + threadIdx.x;   // one 16B chunk each
    int lane = (int)(i & 63);
    size_t t = i >> 6;
    int kc = (int)(t % KC);
    int nt = (int)((t / KC) % (N / 16));
    int e  = (int)(t / KC / (N / 16));
    const float* s = W + ((size_t)e * N + nt * 16 + (lane & 15)) * K
                       + kc * 32 + (lane >> 4) * 8;
    float4 v0 = *(const float4*)s;
    float4 v1 = *(const float4*)(s + 4);
    f16x8 o = { (f16)v0.x,(f16)v0.y,(f16)v0.z,(f16)v0.w,
                (f16)v1.x,(f16)v1.y,(f16)v1.z,(f16)v1.w };
    *(f16x8*)(Wt + i * 8) = o;
}

// ===========================================================================
// Blended expert layer v4:
//   out[b,o] = act( sum_e (bc[b,e]*A[b,:]) . W[e,o,:] + sum_e bc[b,e]*bias[e,o] )
// Wave tile 128(M)x32(N): mt=8 MFMA row-frags x nt=2 col-frags.
//  - B-frag L2 BW at full MFMA rate = 211/mt = 26 B/cyc/CU (ceiling ~56) ✓
//  - A frags read once per k-step, reused across all 8 experts
//  - vscale VALU (512 cyc) : MFMA (2483 cyc @19.4/SIMD) = 0.21 — mostly hidden
// Block 128x128 = 4 waves side by side; grid (N/128, 32) = 1 block/CU;
// blockIdx.x = col-slice -> per-XCD weight slice 2.2 MB, L2-resident.
// A in LDS double-buffered, ONE barrier per k-step; B direct global->VGPR.
// ===========================================================================
template<int K, int N, int ACT, int SRC, typename OT>
__global__ __launch_bounds__(256, 1)
void blended_v4(const f16* __restrict__ A, int ldA,
                const float* __restrict__ x, const float* __restrict__ z,
                const f16* __restrict__ Wt, const float* __restrict__ bias,
                const float* __restrict__ bc, OT* __restrict__ out, int ldOut)
{
    constexpr int KC = K / 32;
    // row stride 40 halves (80 B): frag ds_read_b128 2-way bank alias = free
    __shared__ __align__(16) f16 a_sh[2][128][40];
    __shared__ float bc_sh[128][8];
    __shared__ float bias_sh[8][128];

    const int tid  = threadIdx.x;
    const int col0 = blockIdx.x * 128;   // col-slice -> XCD-local weights
    const int row0 = blockIdx.y * 128;
    const int wave = tid >> 6;           // 0..3 = n-position
    const int lane = tid & 63;
    const int ln   = lane & 15;
    const int quad = lane >> 4;

    // stage bc tile [128][8] and bias tile [8][128]
    for (int i = tid; i < 128 * 8; i += 256)
        bc_sh[i >> 3][i & 7] = bc[(size_t)(row0 + (i >> 3)) * NEXP + (i & 7)];
    for (int i = tid; i < 8 * 128; i += 256)
        bias_sh[i >> 7][i & 127] = bias[(size_t)(i >> 7) * N + col0 + (i & 127)];

    // A staging coords: thread -> (row ar, 16-half chunk ak)
    const int ar = tid >> 1;             // 0..127
    const int ak = (tid & 1) * 16;       // 0 or 16

    auto loadA = [&](int ks, f16x8& lo, f16x8& hi) {
        int k = ks * 32 + ak;            // 16-chunks never straddle XDIM (800%16==0)
        if (SRC == 0) {
            const float* s = (k < XDIM)
                ? x + (size_t)(row0 + ar) * XDIM + k
                : z + (size_t)(row0 + ar) * ZDIM + (k - XDIM);
            float4 v0 = *(const float4*)s;
            float4 v1 = *(const float4*)(s + 4);
            float4 v2 = *(const float4*)(s + 8);
            float4 v3 = *(const float4*)(s + 12);
            lo = (f16x8){ (f16)v0.x,(f16)v0.y,(f16)v0.z,(f16)v0.w,
                          (f16)v1.x,(f16)v1.y,(f16)v1.z,(f16)v1.w };
            hi = (f16x8){ (f16)v2.x,(f16)v2.y,(f16)v2.z,(f16)v2.w,
                          (f16)v3.x,(f16)v3.y,(f16)v3.z,(f16)v3.w };
        } else {
            const f16* s = A + (size_t)(row0 + ar) * ldA + k;
            lo = *(const f16x8*)s;
            hi = *(const f16x8*)(s + 8);
        }
    };

    f16x8 avlo, avhi;
    loadA(0, avlo, avhi);

    __syncthreads();   // bc_sh / bias_sh visible

    // per-lane f16 bc scales for A-frag rows (m = mt*16 + ln)
    f16 bcf[8][8];
    #pragma unroll
    for (int mt = 0; mt < 8; ++mt)
        #pragma unroll
        for (int e = 0; e < 8; ++e)
            bcf[mt][e] = (f16)bc_sh[mt * 16 + ln][e];

    // B pointer for (e=0, first n-tile of this wave); lane-contiguous 16B chunks
    const f16* wp = Wt + ((size_t)(col0 / 16 + wave * 2) * KC) * 512 + lane * 8;
    constexpr size_t ESTR = (size_t)(N / 16) * KC * 512;   // expert stride (halves)
    constexpr size_t TSTR = (size_t)KC * 512;              // n-tile stride

    f32x4 acc[8][2] = {};

    for (int ks = 0; ks < KC; ++ks) {
        const int buf = ks & 1;
        *(f16x8*)&a_sh[buf][ar][ak]     = avlo;
        *(f16x8*)&a_sh[buf][ar][ak + 8] = avhi;
        __syncthreads();   // single barrier per k-step (double-buffered A)

        if (ks + 1 < KC) loadA(ks + 1, avlo, avhi);   // in flight across step

        f16x8 af[8];
        #pragma unroll
        for (int mt = 0; mt < 8; ++mt)
            af[mt] = *(const f16x8*)&a_sh[buf][mt * 16 + ln][quad * 8];

        const f16* wk = wp + (size_t)ks * 512;
        f16x8 b0 = *(const f16x8*)(wk);
        f16x8 b1 = *(const f16x8*)(wk + TSTR);

        #pragma unroll
        for (int e = 0; e < 8; ++e) {
            f16x8 nb0 = b0, nb1 = b1;
            if (e < 7) {
                nb0 = *(const f16x8*)(wk + (size_t)(e + 1) * ESTR);
                nb1 = *(const f16x8*)(wk + (size_t)(e + 1) * ESTR + TSTR);
            }
            #pragma unroll
            for (int mt = 0; mt < 8; ++mt) {
                f16x8 s = vscale(af[mt], bcf[mt][e]);
                acc[mt][0] = __builtin_amdgcn_mfma_f32_16x16x32_f16(s, b0, acc[mt][0], 0,0,0);
                acc[mt][1] = __builtin_amdgcn_mfma_f32_16x16x32_f16(s, b1, acc[mt][1], 0,0,0);
            }
            b0 = nb0; b1 = nb1;
        }
    }

    // epilogue: + sum_e bc*bias, activation, store
    #pragma unroll
    for (int mt = 0; mt < 8; ++mt)
        #pragma unroll
        for (int r = 0; r < 4; ++r) {
            int rl = mt * 16 + quad * 4 + r;
            size_t grow = (size_t)(row0 + rl) * ldOut;
            #pragma unroll
            for (int nt = 0; nt < 2; ++nt) {
                int cl = wave * 32 + nt * 16 + ln;
                float v = acc[mt][nt][r];
                #pragma unroll
                for (int e2 = 0; e2 < NEXP; ++e2)
                    v += bc_sh[rl][e2] * bias_sh[e2][cl];
                if (ACT) v = elu_act(v);
                out[grow + col0 + cl] = (OT)v;
            }
        }
}

// ===========================================================================
extern "C" void kernel_launch(void* const* d_in, const int* in_sizes, int n_in,
                              void* d_out, int out_size, void* d_ws, size_t ws_size,
                              hipStream_t stream)
{
    const float* x   = (const float*)d_in[0];
    const float* z   = (const float*)d_in[1];
    const float* Wg1 = (const float*)d_in[2];
    const float* bg1 = (const float*)d_in[3];
    const float* Wg2 = (const float*)d_in[4];
    const float* bg2 = (const float*)d_in[5];
    const float* Wg3 = (const float*)d_in[6];
    const float* bg3 = (const float*)d_in[7];
    const float* W0  = (const float*)d_in[8];
    const float* b0  = (const float*)d_in[9];
    const float* W1  = (const float*)d_in[10];
    const float* b1  = (const float*)d_in[11];
    const float* W2  = (const float*)d_in[12];
    const float* b2  = (const float*)d_in[13];
    const float* W3  = (const float*)d_in[14];
    const float* b3  = (const float*)d_in[15];
    float* out = (float*)d_out;

    // workspace (~36 MB): wbuf f16 [8*1024*1088] (reused per layer),
    // hz_a/hz_b f16 [4096][1088], bc f32 [4096][8]
    char* ws = (char*)d_ws;
    f16*   wbuf = (f16*)ws;                 ws += (size_t)NEXP * HDIM * (HDIM + ZDIM) * 2;
    f16*   hz_a = (f16*)ws;                 ws += (size_t)BDIM * (HDIM + ZDIM) * 2;
    f16*   hz_b = (f16*)ws;                 ws += (size_t)BDIM * (HDIM + ZDIM) * 2;
    float* bcw  = (float*)ws;

    dim3 blk(256);

    // fused gating MLP + softmax + hz z-column fill
    gating_fused<<<dim3(BDIM / 16), blk, 0, stream>>>(
        x, z, Wg1, bg1, Wg2, bg2, Wg3, bg3, bcw, hz_a, hz_b);

    // blended expert layers: tiled-f16 weight conversion, then frag-direct GEMM
    w_tile<HDIM, XDIM+ZDIM><<<dim3(NEXP*HDIM*(XDIM+ZDIM)/2048), blk, 0, stream>>>(W0, wbuf);
    blended_v4<XDIM+ZDIM, HDIM, 1, 0, f16><<<dim3(HDIM/128, BDIM/128), blk, 0, stream>>>(
        nullptr, 0, x, z, wbuf, b0, bcw, hz_a, HDIM + ZDIM);

    w_tile<HDIM, HDIM+ZDIM><<<dim3(NEXP*HDIM*(HDIM+ZDIM)/2048), blk, 0, stream>>>(W1, wbuf);
    blended_v4<HDIM+ZDIM, HDIM, 1, 1, f16><<<dim3(HDIM/128, BDIM/128), blk, 0, stream>>>(
        hz_a, HDIM + ZDIM, nullptr, nullptr, wbuf, b1, bcw, hz_b, HDIM + ZDIM);

    w_tile<HDIM, HDIM+ZDIM><<<dim3(NEXP*HDIM*(HDIM+ZDIM)/2048), blk, 0, stream>>>(W2, wbuf);
    blended_v4<HDIM+ZDIM, HDIM, 1, 1, f16><<<dim3(HDIM/128, BDIM/128), blk, 0, stream>>>(
        hz_b, HDIM + ZDIM, nullptr, nullptr, wbuf, b2, bcw, hz_a, HDIM + ZDIM);

    w_tile<ODIM, HDIM><<<dim3(NEXP*ODIM*HDIM/2048), blk, 0, stream>>>(W3, wbuf);
    blended_v4<HDIM, ODIM, 0, 1, float><<<dim3(ODIM/128, BDIM/128), blk, 0, stream>>>(
        hz_a, HDIM + ZDIM, nullptr, nullptr, wbuf, b3, bcw, out, ODIM);
}